// Round 14
// baseline (148.918 us; speedup 1.0000x reference)
//
#include <hip/hip_runtime.h>
#include <hip/hip_bf16.h>

typedef __attribute__((ext_vector_type(8))) short bf16x8;
typedef __attribute__((ext_vector_type(4))) float f32x4;

#define DEV static __device__ __forceinline__

DEV unsigned short f2bf(float f) {
    union { __hip_bfloat16 h; unsigned short u; } cv;
    cv.h = __float2bfloat16(f);
    return cv.u;
}

DEV bf16x8 cvt8(f32x4 lo, f32x4 hi) {
    bf16x8 u;
    u[0] = (short)f2bf(lo[0]); u[1] = (short)f2bf(lo[1]);
    u[2] = (short)f2bf(lo[2]); u[3] = (short)f2bf(lo[3]);
    u[4] = (short)f2bf(hi[0]); u[5] = (short)f2bf(hi[1]);
    u[6] = (short)f2bf(hi[2]); u[7] = (short)f2bf(hi[3]);
    return u;
}

typedef __attribute__((address_space(1))) const void gas_t;
typedef __attribute__((address_space(3))) void las_t;

DEV void gl_lds16(const void* g, void* l) {
    __builtin_amdgcn_global_load_lds((gas_t*)g, (las_t*)l, 16, 0, 0);
}

// ---------------------------------------------------------------------------
// Kernel 1 (unchanged): W [3][512][512] fp32 -> WT bf16 transposed.
// W0 pre-scaled by 1/sqrt(512).
// ---------------------------------------------------------------------------
__global__ __launch_bounds__(256, 2) void wt_kernel(const float* __restrict__ W,
                                                    unsigned short* __restrict__ WT) {
    __shared__ __align__(16) unsigned short T[64][72];
    int bid = blockIdx.x;
    int w = bid >> 6;
    int rem = bid & 63;
    int kt = rem >> 3, nt = rem & 7;
    int t = threadIdx.x;
    int r = t >> 2, cq = t & 3;
    const float* src = W + ((size_t)(w * 512 + kt * 64 + r)) * 512 + nt * 64 + cq * 16;
    float sc = (w == 0) ? 0.04419417382415922f : 1.0f;  // 1/sqrt(512)
    #pragma unroll
    for (int i = 0; i < 4; i++) {
        float4 f = *(const float4*)(src + 4 * i);
        T[r][cq * 16 + 4 * i + 0] = f2bf(f.x * sc);
        T[r][cq * 16 + 4 * i + 1] = f2bf(f.y * sc);
        T[r][cq * 16 + 4 * i + 2] = f2bf(f.z * sc);
        T[r][cq * 16 + 4 * i + 3] = f2bf(f.w * sc);
    }
    __syncthreads();
    int n = t >> 2, kq = t & 3;
    bf16x8 v0, v1;
    #pragma unroll
    for (int e = 0; e < 8; e++) v0[e] = (short)T[kq * 16 + e][n];
    #pragma unroll
    for (int e = 0; e < 8; e++) v1[e] = (short)T[kq * 16 + 8 + e][n];
    unsigned short* dst = WT + ((size_t)(w * 512 + nt * 64 + n)) * 512 + kt * 64 + kq * 16;
    *(bf16x8*)dst = v0;
    *(bf16x8*)(dst + 8) = v1;
}

// ---------------------------------------------------------------------------
// Kernel 2 (v16): proj with T3+T4 pipeline — 3-stage staging buffers +
// counted vmcnt + raw barriers. v11/v15's per-iter __syncthreads emitted
// s_waitcnt vmcnt(0): 16 full DMA drains with ~80cy of MFMA each to hide
// 200-900cy latency. Now: wait vmcnt(12) (own STAGE(kk) done) -> s_barrier ->
// ds_read frags -> lgkmcnt(0) -> s_barrier -> issue STAGE(kk+3) -> MFMA.
// Loads for kk+1/kk+2 fly across both barriers. buf[kk%3] is only rewritten
// by STAGE(kk+3), issued after barrier2 proves all waves' reads retired.
// LDS: As 3x16KB + Bs 3x8KB = 72KB -> still 2 blocks/CU; Cs overlays.
// ---------------------------------------------------------------------------
#define STAGE_P3(kk) do {                                                         \
    int buf_ = (kk) % 3;                                                          \
    _Pragma("unroll")                                                             \
    for (int i_ = 0; i_ < 4; i_++) {   /* A: fp32, 8 rows/wave/iter */            \
        int r_ = wid * 32 + i_ * 8 + (lane >> 3);                                 \
        int ch_ = (lane & 7) ^ (r_ & 7);                                          \
        gl_lds16(xp + (size_t)r_ * 512 + (kk) * 32 + ch_ * 4,                     \
                 &As[buf_ * 4096 + (wid * 32 + i_ * 8) * 32]);                    \
    }                                                                             \
    _Pragma("unroll")                                                             \
    for (int j_ = 0; j_ < 2; j_++) {   /* B: bf16, 16 rows/wave/iter */           \
        int r_ = wid * 32 + j_ * 16 + (lane >> 2);                                \
        int ch_ = (lane & 3) ^ (r_ & 3);                                          \
        gl_lds16(wp + (size_t)r_ * 512 + (kk) * 32 + ch_ * 8,                     \
                 &Bs[buf_ * 4096 + (wid * 32 + j_ * 16) * 32]);                   \
    }                                                                             \
} while (0)

__global__ __launch_bounds__(256, 2) void proj_kernel(const float* __restrict__ x,
        const unsigned short* __restrict__ WT,
        unsigned short* __restrict__ Qo, unsigned short* __restrict__ Ko,
        unsigned short* __restrict__ VTo) {
    __shared__ __align__(16) char smem[73728];             // 72 KB
    float* As = (float*)smem;                              // [3][128*32] fp32 48KB
    unsigned short* Bs = (unsigned short*)(smem + 49152);  // [3][128*32] bf16 24KB
    unsigned short* Cs = (unsigned short*)smem;            // [128][136] (post-loop)

    int bid = blockIdx.x;
    int swz = (bid & 7) * 192 + (bid >> 3);
    int mt = swz / 12;
    int rem = swz - mt * 12;
    int w = rem >> 2, nt = rem & 3;
    int tid = threadIdx.x;
    int lane = tid & 63, wid = tid >> 6;
    int wm = wid >> 1, wn = wid & 1;
    int c = lane & 15, g = lane >> 4;

    const float* xp = x + (size_t)(mt * 128) * 512;
    const unsigned short* wp = WT + ((size_t)(w * 512 + nt * 128)) * 512;

    const f32x4 fz = {0.f, 0.f, 0.f, 0.f};
    f32x4 acc[4][4];
    #pragma unroll
    for (int i = 0; i < 4; i++)
        #pragma unroll
        for (int j = 0; j < 4; j++) acc[i][j] = fz;

    STAGE_P3(0);
    STAGE_P3(1);
    STAGE_P3(2);
    for (int kk = 0; kk < 16; kk++) {
        // wait for own STAGE(kk) loads (oldest 6) without draining the queue
        if (kk < 14)      asm volatile("s_waitcnt vmcnt(12)" ::: "memory");
        else if (kk == 14) asm volatile("s_waitcnt vmcnt(6)" ::: "memory");
        else               asm volatile("s_waitcnt vmcnt(0)" ::: "memory");
        __builtin_amdgcn_s_barrier();    // buf[kk%3] fully staged by all waves

        const float* Ac = &As[(kk % 3) * 4096];
        const unsigned short* Bc = &Bs[(kk % 3) * 4096];
        bf16x8 a[4], bb[4];
        #pragma unroll
        for (int rt = 0; rt < 4; rt++) {
            int row = wm * 64 + rt * 16 + c;
            f32x4 lo = *(const f32x4*)&Ac[row * 32 + (((2 * g) ^ (row & 7)) * 4)];
            f32x4 hi = *(const f32x4*)&Ac[row * 32 + (((2 * g + 1) ^ (row & 7)) * 4)];
            a[rt] = cvt8(lo, hi);
        }
        #pragma unroll
        for (int ct = 0; ct < 4; ct++) {
            int row = wn * 64 + ct * 16 + c;
            bb[ct] = *(const bf16x8*)&Bc[row * 32 + ((g ^ (row & 3)) * 8)];
        }
        asm volatile("s_waitcnt lgkmcnt(0)" ::: "memory");
        __builtin_amdgcn_s_barrier();    // all waves' reads of buf[kk%3] retired
        if (kk + 3 < 16) STAGE_P3(kk + 3);  // safe to rewrite buf[kk%3]

        #pragma unroll
        for (int rt = 0; rt < 4; rt++)
            #pragma unroll
            for (int ct = 0; ct < 4; ct++)
                acc[rt][ct] = __builtin_amdgcn_mfma_f32_16x16x32_bf16(a[rt], bb[ct], acc[rt][ct], 0, 0, 0);
    }

    // ---- epilogue: stage the 128x128 bf16 tile into Cs (stride 136)
    __syncthreads();                     // all LDS traffic retired before overlay
    #pragma unroll
    for (int rt = 0; rt < 4; rt++)
        #pragma unroll
        for (int ct = 0; ct < 4; ct++)
            #pragma unroll
            for (int r = 0; r < 4; r++)
                Cs[(wm * 64 + rt * 16 + g * 4 + r) * 136 + (wn * 64 + ct * 16 + c)] = f2bf(acc[rt][ct][r]);
    __syncthreads();

    if (w < 2) {
        // Q/K: row-major, coalesced — 16 lanes cover one 256B row segment
        unsigned short* dst = (w == 0) ? Qo : Ko;
        int rr = tid >> 4;               // 0..15
        int cc8 = (tid & 15) * 8;        // 0..120
        #pragma unroll
        for (int jj = 0; jj < 8; jj++) {
            int row = jj * 16 + rr;
            bf16x8 v = *(const bf16x8*)&Cs[row * 136 + cc8];
            *(bf16x8*)(dst + (size_t)(mt * 128 + row) * 512 + nt * 128 + cc8) = v;
        }
    } else {
        // V: transposed out of Cs (stride 136)
        int dcol = tid >> 1, sh = tid & 1;
        int bb2 = mt >> 4;
        int s0r = (mt & 15) * 128;
        #pragma unroll
        for (int jj = 0; jj < 8; jj++) {
            bf16x8 v;
            #pragma unroll
            for (int e = 0; e < 8; e++) v[e] = (short)Cs[(sh * 64 + jj * 8 + e) * 136 + dcol];
            *(bf16x8*)(VTo + ((size_t)(bb2 * 512 + nt * 128 + dcol)) * 2048 + s0r + sh * 64 + jj * 8) = v;
        }
    }
}

// ---------------------------------------------------------------------------
// Kernel 3 (v10/v8 verbatim, FROZEN): wave-specialized flash attention
// + PV V-tile prefetch. 113.4 us. Five micro-scheduling experiments (setprio
// x2, chain-split, Ps pad, Ps swizzle) were all null/negative; the residual
// bank conflicts are the K-read structural minimum. Do not touch.
// ---------------------------------------------------------------------------
#define STAGE_K(tt) do {                                                        \
    _Pragma("unroll")                                                           \
    for (int i_ = 0; i_ < 4; i_++) {                                            \
        int r_ = wid * 4 + i_;                                                  \
        gl_lds16(Kb + (size_t)((tt) * 64 + r_) * 512 + ((lane ^ (r_ & 7)) * 8), \
                 &Ks[(tt) & 1][r_ * 512]);                                      \
    }                                                                           \
} while (0)

__global__ __launch_bounds__(1024, 4) void attn_kernel(const unsigned short* __restrict__ Qg,
        const unsigned short* __restrict__ Kg, const unsigned short* __restrict__ VTg,
        float* __restrict__ out) {
    __shared__ __align__(16) unsigned short Ks[2][64 * 512];  // 128 KB, swizzled
    __shared__ __align__(16) unsigned short Ps[2][64][72];    // 18.4 KB, dbuf
    __shared__ float psum_s[64][2];

    int bid = blockIdx.x;
    int swz = (bid & 7) * 32 + (bid >> 3);  // XCD x owns batch x
    int b = swz >> 5, qt = swz & 31;
    int tid = threadIdx.x;
    int lane = tid & 63, wid = tid >> 6;    // wid 0..15
    int c = lane & 15, g = lane >> 4;

    const unsigned short* Qb = Qg + ((size_t)(b * 2048 + qt * 64)) * 512;
    const unsigned short* Kb = Kg + ((size_t)b * 2048) * 512;
    const unsigned short* Vb = VTg + ((size_t)b * 512) * 2048;

    // ---- stage Q (swizzled source) into Ks[0] — all waves
    #pragma unroll
    for (int i = 0; i < 4; i++) {
        int r = wid * 4 + i;
        gl_lds16(Qb + (size_t)r * 512 + ((lane ^ (r & 7)) * 8), &Ks[0][r * 512]);
    }

    if (wid < 8) {
        // ================= score waves =================
        int sqg = wid >> 1;          // q-row group (0..3), two waves each
        int skg = (wid & 1) * 2;     // first of two 16-col kv groups (0 or 2)
        __syncthreads();             // A: Q DMA done (vmcnt0)
        bf16x8 qf[16];
        {
            int row = sqg * 16 + c;
            #pragma unroll
            for (int ks = 0; ks < 16; ks++)
                qf[ks] = *(const bf16x8*)&Ks[0][row * 512 + (((ks * 4 + g) ^ (row & 7)) * 8)];
        }
        __syncthreads();             // B: Q reads done before K(0) overwrite
        STAGE_K(0);

        float accs[8];
        #pragma unroll
        for (int j = 0; j < 8; j++) accs[j] = 0.0f;

        for (int t = 0; t < 32; t++) {
            __syncthreads();         // K(t) staged; Ps(t) buffer free
            if (t + 1 < 32) STAGE_K(t + 1);

            const unsigned short* KsC = &Ks[t & 1][0];
            const f32x4 fz = {0.f, 0.f, 0.f, 0.f};
            f32x4 s0 = fz, s1 = fz;
            int kr0 = skg * 16 + c;
            int kr1 = kr0 + 16;
            #pragma unroll
            for (int ks = 0; ks < 16; ks++) {
                bf16x8 bk0 = *(const bf16x8*)&KsC[kr0 * 512 + (((ks * 4 + g) ^ (kr0 & 7)) * 8)];
                bf16x8 bk1 = *(const bf16x8*)&KsC[kr1 * 512 + (((ks * 4 + g) ^ (kr1 & 7)) * 8)];
                s0 = __builtin_amdgcn_mfma_f32_16x16x32_bf16(qf[ks], bk0, s0, 0, 0, 0);
                s1 = __builtin_amdgcn_mfma_f32_16x16x32_bf16(qf[ks], bk1, s1, 0, 0, 0);
            }
            unsigned short* PsW = &Ps[t & 1][0][0];
            #pragma unroll
            for (int r = 0; r < 4; r++) {
                int row = sqg * 16 + g * 4 + r;
                float p0 = __expf(s0[r]);
                float p1 = __expf(s1[r]);
                accs[r] += p0;
                accs[4 + r] += p1;
                PsW[row * 72 + skg * 16 + c] = f2bf(p0);
                PsW[row * 72 + (skg + 1) * 16 + c] = f2bf(p1);
            }
        }

        // final row-sum reduction into psum_s
        #pragma unroll
        for (int r = 0; r < 4; r++) {
            float v = accs[r] + accs[4 + r];
            v += __shfl_xor(v, 1);
            v += __shfl_xor(v, 2);
            v += __shfl_xor(v, 4);
            v += __shfl_xor(v, 8);
            if (c == 0) psum_s[sqg * 16 + g * 4 + r][wid & 1] = v;
        }
        __syncthreads();             // C: Ps(31) + psum_s published
    } else {
        // ================= PV waves =================
        int pcol = (wid - 8) * 64;   // d-column base (0..448)
        const unsigned short* Vp = Vb + (size_t)(pcol + c) * 2048 + g * 8;
        __syncthreads();             // A
        __syncthreads();             // B
        STAGE_K(0);

        f32x4 o[16];
        {
            const f32x4 fz = {0.f, 0.f, 0.f, 0.f};
            #pragma unroll
            for (int i = 0; i < 16; i++) o[i] = fz;
        }
        bf16x8 bva[4];               // V(t, h0) prefetched one tile ahead
        #pragma unroll
        for (int ct = 0; ct < 4; ct++)
            bva[ct] = *(const bf16x8*)(Vp + (size_t)(ct * 16) * 2048);

        for (int t = 0; t < 32; t++) {
            __syncthreads();         // K(t) staged; Ps(t-1) visible
            if (t + 1 < 32) STAGE_K(t + 1);
            if (t > 0) {
                int tp = t - 1;
                const unsigned short* PsR = &Ps[tp & 1][0][0];
                bf16x8 bvb[4];       // V(tp, h1): issue now, use after h0 MFMAs
                #pragma unroll
                for (int ct = 0; ct < 4; ct++)
                    bvb[ct] = *(const bf16x8*)(Vp + (size_t)(ct * 16) * 2048 + tp * 64 + 32);
                #pragma unroll
                for (int rt = 0; rt < 4; rt++) {
                    bf16x8 pa = *(const bf16x8*)&PsR[(rt * 16 + c) * 72 + g * 8];
                    #pragma unroll
                    for (int ct = 0; ct < 4; ct++)
                        o[rt * 4 + ct] = __builtin_amdgcn_mfma_f32_16x16x32_bf16(
                            pa, bva[ct], o[rt * 4 + ct], 0, 0, 0);
                }
                #pragma unroll
                for (int ct = 0; ct < 4; ct++)   // prefetch V(t, h0) for next tile
                    bva[ct] = *(const bf16x8*)(Vp + (size_t)(ct * 16) * 2048 + t * 64);
                #pragma unroll
                for (int rt = 0; rt < 4; rt++) {
                    bf16x8 pa = *(const bf16x8*)&PsR[(rt * 16 + c) * 72 + 32 + g * 8];
                    #pragma unroll
                    for (int ct = 0; ct < 4; ct++)
                        o[rt * 4 + ct] = __builtin_amdgcn_mfma_f32_16x16x32_bf16(
                            pa, bvb[ct], o[rt * 4 + ct], 0, 0, 0);
                }
            }
        }
        __syncthreads();             // C: Ps(31) + psum_s visible
        {
            const unsigned short* PsR = &Ps[31 & 1][0][0];
            bf16x8 bvb[4];
            #pragma unroll
            for (int ct = 0; ct < 4; ct++)
                bvb[ct] = *(const bf16x8*)(Vp + (size_t)(ct * 16) * 2048 + 31 * 64 + 32);
            #pragma unroll
            for (int rt = 0; rt < 4; rt++) {
                bf16x8 pa = *(const bf16x8*)&PsR[(rt * 16 + c) * 72 + g * 8];
                #pragma unroll
                for (int ct = 0; ct < 4; ct++)
                    o[rt * 4 + ct] = __builtin_amdgcn_mfma_f32_16x16x32_bf16(
                        pa, bva[ct], o[rt * 4 + ct], 0, 0, 0);
            }
            #pragma unroll
            for (int rt = 0; rt < 4; rt++) {
                bf16x8 pa = *(const bf16x8*)&PsR[(rt * 16 + c) * 72 + 32 + g * 8];
                #pragma unroll
                for (int ct = 0; ct < 4; ct++)
                    o[rt * 4 + ct] = __builtin_amdgcn_mfma_f32_16x16x32_bf16(
                        pa, bvb[ct], o[rt * 4 + ct], 0, 0, 0);
            }
        }

        float* ob = out + ((size_t)(b * 2048 + qt * 64)) * 512;
        #pragma unroll
        for (int rt = 0; rt < 4; rt++)
            #pragma unroll
            for (int r = 0; r < 4; r++) {
                int lrow = rt * 16 + g * 4 + r;
                float l = psum_s[lrow][0] + psum_s[lrow][1];
                float inv = 1.0f / l;
                #pragma unroll
                for (int ct = 0; ct < 4; ct++)
                    ob[(size_t)lrow * 512 + pcol + ct * 16 + c] = o[rt * 4 + ct][r] * inv;
            }
    }
}

// ---------------------------------------------------------------------------
extern "C" void kernel_launch(void* const* d_in, const int* in_sizes, int n_in,
                              void* d_out, int out_size, void* d_ws, size_t ws_size,
                              hipStream_t stream) {
    const float* x = (const float*)d_in[0];   // [8][2048][512] fp32
    const float* W = (const float*)d_in[1];   // [3][512][512] fp32
    float* out = (float*)d_out;               // [8][2048][512] fp32
    char* ws = (char*)d_ws;
    unsigned short* WT = (unsigned short*)(ws);
    unsigned short* Q  = (unsigned short*)(ws + (size_t)2  * 1024 * 1024);
    unsigned short* K  = (unsigned short*)(ws + (size_t)18 * 1024 * 1024);
    unsigned short* VT = (unsigned short*)(ws + (size_t)34 * 1024 * 1024);

    wt_kernel<<<192, 256, 0, stream>>>(W, WT);
    proj_kernel<<<1536, 256, 0, stream>>>(x, WT, Q, K, VT);
    attn_kernel<<<256, 1024, 0, stream>>>(Q, K, VT, out);
}

// Round 15
// 147.304 us; speedup vs baseline: 1.0110x; 1.0110x over previous
//
#include <hip/hip_runtime.h>
#include <hip/hip_bf16.h>

typedef __attribute__((ext_vector_type(8))) short bf16x8;
typedef __attribute__((ext_vector_type(4))) float f32x4;

#define DEV static __device__ __forceinline__

DEV unsigned short f2bf(float f) {
    union { __hip_bfloat16 h; unsigned short u; } cv;
    cv.h = __float2bfloat16(f);
    return cv.u;
}

DEV bf16x8 cvt8(f32x4 lo, f32x4 hi) {
    bf16x8 u;
    u[0] = (short)f2bf(lo[0]); u[1] = (short)f2bf(lo[1]);
    u[2] = (short)f2bf(lo[2]); u[3] = (short)f2bf(lo[3]);
    u[4] = (short)f2bf(hi[0]); u[5] = (short)f2bf(hi[1]);
    u[6] = (short)f2bf(hi[2]); u[7] = (short)f2bf(hi[3]);
    return u;
}

typedef __attribute__((address_space(1))) const void gas_t;
typedef __attribute__((address_space(3))) void las_t;

DEV void gl_lds16(const void* g, void* l) {
    __builtin_amdgcn_global_load_lds((gas_t*)g, (las_t*)l, 16, 0, 0);
}

// ---------------------------------------------------------------------------
// Kernel 1 (unchanged): W [3][512][512] fp32 -> WT bf16 transposed.
// W0 pre-scaled by 1/sqrt(512).
// ---------------------------------------------------------------------------
__global__ __launch_bounds__(256, 2) void wt_kernel(const float* __restrict__ W,
                                                    unsigned short* __restrict__ WT) {
    __shared__ __align__(16) unsigned short T[64][72];
    int bid = blockIdx.x;
    int w = bid >> 6;
    int rem = bid & 63;
    int kt = rem >> 3, nt = rem & 7;
    int t = threadIdx.x;
    int r = t >> 2, cq = t & 3;
    const float* src = W + ((size_t)(w * 512 + kt * 64 + r)) * 512 + nt * 64 + cq * 16;
    float sc = (w == 0) ? 0.04419417382415922f : 1.0f;  // 1/sqrt(512)
    #pragma unroll
    for (int i = 0; i < 4; i++) {
        float4 f = *(const float4*)(src + 4 * i);
        T[r][cq * 16 + 4 * i + 0] = f2bf(f.x * sc);
        T[r][cq * 16 + 4 * i + 1] = f2bf(f.y * sc);
        T[r][cq * 16 + 4 * i + 2] = f2bf(f.z * sc);
        T[r][cq * 16 + 4 * i + 3] = f2bf(f.w * sc);
    }
    __syncthreads();
    int n = t >> 2, kq = t & 3;
    bf16x8 v0, v1;
    #pragma unroll
    for (int e = 0; e < 8; e++) v0[e] = (short)T[kq * 16 + e][n];
    #pragma unroll
    for (int e = 0; e < 8; e++) v1[e] = (short)T[kq * 16 + 8 + e][n];
    unsigned short* dst = WT + ((size_t)(w * 512 + nt * 64 + n)) * 512 + kt * 64 + kq * 16;
    *(bf16x8*)dst = v0;
    *(bf16x8*)(dst + 8) = v1;
}

// ---------------------------------------------------------------------------
// Kernel 2 (v17): proj re-tiled to 64x256 output blocks. Grid 1536 = 256
// row-slabs x 3 w x 2 col-halves. Each 64-row x slab is now read by 6 blocks
// (was 12) -> L3 x-traffic 384->192 MB. Staging = As 16KB + Bs 32KB = 48KB ->
// (256,3) gives 3 blocks/CU (12 waves/CU, was 8); grid = exactly 2 residency
// rounds. Per-wave footprint identical to v11 (acc[4][4], ~121 regs).
// Schedule = v11's 1-barrier/kk (v16's counted-vmcnt regressed; reverted).
// ---------------------------------------------------------------------------
#define STAGE_P(kk) do {                                                          \
    _Pragma("unroll")                                                             \
    for (int i_ = 0; i_ < 2; i_++) {   /* A: fp32, 64 rows, 8 rows/wave/iter */   \
        int r_ = wid * 16 + i_ * 8 + (lane >> 3);                                 \
        int ch_ = (lane & 7) ^ (r_ & 7);                                          \
        gl_lds16(xp + (size_t)r_ * 512 + (kk) * 32 + ch_ * 4,                     \
                 &As[((kk) & 1) * 2048 + (wid * 16 + i_ * 8) * 32]);              \
    }                                                                             \
    _Pragma("unroll")                                                             \
    for (int j_ = 0; j_ < 4; j_++) {   /* B: bf16, 256 rows, 16 rows/wave/iter */ \
        int r_ = wid * 64 + j_ * 16 + (lane >> 2);                                \
        int ch_ = (lane & 3) ^ (r_ & 3);                                          \
        gl_lds16(wp + (size_t)r_ * 512 + (kk) * 32 + ch_ * 8,                     \
                 &Bs[((kk) & 1) * 8192 + (wid * 64 + j_ * 16) * 32]);             \
    }                                                                             \
} while (0)

__global__ __launch_bounds__(256, 3) void proj_kernel(const float* __restrict__ x,
        const unsigned short* __restrict__ WT,
        unsigned short* __restrict__ Qo, unsigned short* __restrict__ Ko,
        unsigned short* __restrict__ VTo) {
    __shared__ __align__(16) char smem[49152];             // 48 KB
    float* As = (float*)smem;                              // [2][64*32] fp32 16KB
    unsigned short* Bs = (unsigned short*)(smem + 16384);  // [2][256*32] bf16 32KB
    unsigned short* Cs = (unsigned short*)smem;            // [64][264] (post-loop)

    int bid = blockIdx.x;
    int swz = (bid & 7) * 192 + (bid >> 3);   // XCD-contiguous
    int mt = swz / 6;                          // 64-row slab, 0..255
    int rem = swz - mt * 6;
    int w = rem >> 1, np = rem & 1;            // w 0..2; col half 0..1 (256 cols)
    int tid = threadIdx.x;
    int lane = tid & 63, wid = tid >> 6;       // wave = 64 rows x 64 cols
    int c = lane & 15, g = lane >> 4;

    const float* xp = x + (size_t)(mt * 64) * 512;
    const unsigned short* wp = WT + ((size_t)(w * 512 + np * 256)) * 512;

    const f32x4 fz = {0.f, 0.f, 0.f, 0.f};
    f32x4 acc[4][4];
    #pragma unroll
    for (int i = 0; i < 4; i++)
        #pragma unroll
        for (int j = 0; j < 4; j++) acc[i][j] = fz;

    STAGE_P(0);
    for (int kk = 0; kk < 16; kk++) {
        __syncthreads();                 // buf[kk&1] DMA drained (vmcnt0)
        if (kk + 1 < 16) STAGE_P(kk + 1);
        const float* Ac = &As[(kk & 1) * 2048];
        const unsigned short* Bc = &Bs[(kk & 1) * 8192];
        bf16x8 a[4], bb[4];
        #pragma unroll
        for (int rt = 0; rt < 4; rt++) {
            int row = rt * 16 + c;
            f32x4 lo = *(const f32x4*)&Ac[row * 32 + (((2 * g) ^ (row & 7)) * 4)];
            f32x4 hi = *(const f32x4*)&Ac[row * 32 + (((2 * g + 1) ^ (row & 7)) * 4)];
            a[rt] = cvt8(lo, hi);
        }
        #pragma unroll
        for (int ct = 0; ct < 4; ct++) {
            int row = wid * 64 + ct * 16 + c;
            bb[ct] = *(const bf16x8*)&Bc[row * 32 + ((g ^ (row & 3)) * 8)];
        }
        __builtin_amdgcn_s_setprio(1);
        #pragma unroll
        for (int rt = 0; rt < 4; rt++)
            #pragma unroll
            for (int ct = 0; ct < 4; ct++)
                acc[rt][ct] = __builtin_amdgcn_mfma_f32_16x16x32_bf16(a[rt], bb[ct], acc[rt][ct], 0, 0, 0);
        __builtin_amdgcn_s_setprio(0);
    }

    // ---- epilogue: stage the 64x256 bf16 tile into Cs (stride 264)
    __syncthreads();                     // all As/Bs reads retired before overlay
    #pragma unroll
    for (int rt = 0; rt < 4; rt++)
        #pragma unroll
        for (int ct = 0; ct < 4; ct++)
            #pragma unroll
            for (int r = 0; r < 4; r++)
                Cs[(rt * 16 + g * 4 + r) * 264 + (wid * 64 + ct * 16 + c)] = f2bf(acc[rt][ct][r]);
    __syncthreads();

    if (w < 2) {
        // Q/K: row-major, coalesced — 16 lanes cover one 256B row segment
        unsigned short* dst = (w == 0) ? Qo : Ko;
        int rr = tid >> 4;               // 0..15
        int cc8 = (tid & 15) * 8;        // 0..120
        #pragma unroll
        for (int jj = 0; jj < 4; jj++) {
            int row = jj * 16 + rr;
            #pragma unroll
            for (int ch = 0; ch < 2; ch++) {
                bf16x8 v = *(const bf16x8*)&Cs[row * 264 + ch * 128 + cc8];
                *(bf16x8*)(dst + (size_t)(mt * 64 + row) * 512 + np * 256 + ch * 128 + cc8) = v;
            }
        }
    } else {
        // V: transposed out of Cs -> VT [8][512][2048]
        int b2 = mt >> 5;                // batch
        int s0r = (mt & 31) * 64;        // s base within batch
        int dcol = tid >> 1, sh = tid & 1;
        #pragma unroll
        for (int ch = 0; ch < 2; ch++) {
            int dcol2 = ch * 128 + dcol;
            #pragma unroll
            for (int jj = 0; jj < 4; jj++) {
                bf16x8 v;
                #pragma unroll
                for (int e = 0; e < 8; e++) v[e] = (short)Cs[(sh * 32 + jj * 8 + e) * 264 + dcol2];
                *(bf16x8*)(VTo + ((size_t)(b2 * 512 + np * 256 + dcol2)) * 2048 + s0r + sh * 32 + jj * 8) = v;
            }
        }
    }
}

// ---------------------------------------------------------------------------
// Kernel 3 (v10/v8 verbatim, FROZEN): wave-specialized flash attention
// + PV V-tile prefetch. 113.4 us. Six scheduling/bank experiments were all
// null/negative; residual conflicts are the K-read structural minimum.
// ---------------------------------------------------------------------------
#define STAGE_K(tt) do {                                                        \
    _Pragma("unroll")                                                           \
    for (int i_ = 0; i_ < 4; i_++) {                                            \
        int r_ = wid * 4 + i_;                                                  \
        gl_lds16(Kb + (size_t)((tt) * 64 + r_) * 512 + ((lane ^ (r_ & 7)) * 8), \
                 &Ks[(tt) & 1][r_ * 512]);                                      \
    }                                                                           \
} while (0)

__global__ __launch_bounds__(1024, 4) void attn_kernel(const unsigned short* __restrict__ Qg,
        const unsigned short* __restrict__ Kg, const unsigned short* __restrict__ VTg,
        float* __restrict__ out) {
    __shared__ __align__(16) unsigned short Ks[2][64 * 512];  // 128 KB, swizzled
    __shared__ __align__(16) unsigned short Ps[2][64][72];    // 18.4 KB, dbuf
    __shared__ float psum_s[64][2];

    int bid = blockIdx.x;
    int swz = (bid & 7) * 32 + (bid >> 3);  // XCD x owns batch x
    int b = swz >> 5, qt = swz & 31;
    int tid = threadIdx.x;
    int lane = tid & 63, wid = tid >> 6;    // wid 0..15
    int c = lane & 15, g = lane >> 4;

    const unsigned short* Qb = Qg + ((size_t)(b * 2048 + qt * 64)) * 512;
    const unsigned short* Kb = Kg + ((size_t)b * 2048) * 512;
    const unsigned short* Vb = VTg + ((size_t)b * 512) * 2048;

    // ---- stage Q (swizzled source) into Ks[0] — all waves
    #pragma unroll
    for (int i = 0; i < 4; i++) {
        int r = wid * 4 + i;
        gl_lds16(Qb + (size_t)r * 512 + ((lane ^ (r & 7)) * 8), &Ks[0][r * 512]);
    }

    if (wid < 8) {
        // ================= score waves =================
        int sqg = wid >> 1;          // q-row group (0..3), two waves each
        int skg = (wid & 1) * 2;     // first of two 16-col kv groups (0 or 2)
        __syncthreads();             // A: Q DMA done (vmcnt0)
        bf16x8 qf[16];
        {
            int row = sqg * 16 + c;
            #pragma unroll
            for (int ks = 0; ks < 16; ks++)
                qf[ks] = *(const bf16x8*)&Ks[0][row * 512 + (((ks * 4 + g) ^ (row & 7)) * 8)];
        }
        __syncthreads();             // B: Q reads done before K(0) overwrite
        STAGE_K(0);

        float accs[8];
        #pragma unroll
        for (int j = 0; j < 8; j++) accs[j] = 0.0f;

        for (int t = 0; t < 32; t++) {
            __syncthreads();         // K(t) staged; Ps(t) buffer free
            if (t + 1 < 32) STAGE_K(t + 1);

            const unsigned short* KsC = &Ks[t & 1][0];
            const f32x4 fz = {0.f, 0.f, 0.f, 0.f};
            f32x4 s0 = fz, s1 = fz;
            int kr0 = skg * 16 + c;
            int kr1 = kr0 + 16;
            #pragma unroll
            for (int ks = 0; ks < 16; ks++) {
                bf16x8 bk0 = *(const bf16x8*)&KsC[kr0 * 512 + (((ks * 4 + g) ^ (kr0 & 7)) * 8)];
                bf16x8 bk1 = *(const bf16x8*)&KsC[kr1 * 512 + (((ks * 4 + g) ^ (kr1 & 7)) * 8)];
                s0 = __builtin_amdgcn_mfma_f32_16x16x32_bf16(qf[ks], bk0, s0, 0, 0, 0);
                s1 = __builtin_amdgcn_mfma_f32_16x16x32_bf16(qf[ks], bk1, s1, 0, 0, 0);
            }
            unsigned short* PsW = &Ps[t & 1][0][0];
            #pragma unroll
            for (int r = 0; r < 4; r++) {
                int row = sqg * 16 + g * 4 + r;
                float p0 = __expf(s0[r]);
                float p1 = __expf(s1[r]);
                accs[r] += p0;
                accs[4 + r] += p1;
                PsW[row * 72 + skg * 16 + c] = f2bf(p0);
                PsW[row * 72 + (skg + 1) * 16 + c] = f2bf(p1);
            }
        }

        // final row-sum reduction into psum_s
        #pragma unroll
        for (int r = 0; r < 4; r++) {
            float v = accs[r] + accs[4 + r];
            v += __shfl_xor(v, 1);
            v += __shfl_xor(v, 2);
            v += __shfl_xor(v, 4);
            v += __shfl_xor(v, 8);
            if (c == 0) psum_s[sqg * 16 + g * 4 + r][wid & 1] = v;
        }
        __syncthreads();             // C: Ps(31) + psum_s published
    } else {
        // ================= PV waves =================
        int pcol = (wid - 8) * 64;   // d-column base (0..448)
        const unsigned short* Vp = Vb + (size_t)(pcol + c) * 2048 + g * 8;
        __syncthreads();             // A
        __syncthreads();             // B
        STAGE_K(0);

        f32x4 o[16];
        {
            const f32x4 fz = {0.f, 0.f, 0.f, 0.f};
            #pragma unroll
            for (int i = 0; i < 16; i++) o[i] = fz;
        }
        bf16x8 bva[4];               // V(t, h0) prefetched one tile ahead
        #pragma unroll
        for (int ct = 0; ct < 4; ct++)
            bva[ct] = *(const bf16x8*)(Vp + (size_t)(ct * 16) * 2048);

        for (int t = 0; t < 32; t++) {
            __syncthreads();         // K(t) staged; Ps(t-1) visible
            if (t + 1 < 32) STAGE_K(t + 1);
            if (t > 0) {
                int tp = t - 1;
                const unsigned short* PsR = &Ps[tp & 1][0][0];
                bf16x8 bvb[4];       // V(tp, h1): issue now, use after h0 MFMAs
                #pragma unroll
                for (int ct = 0; ct < 4; ct++)
                    bvb[ct] = *(const bf16x8*)(Vp + (size_t)(ct * 16) * 2048 + tp * 64 + 32);
                #pragma unroll
                for (int rt = 0; rt < 4; rt++) {
                    bf16x8 pa = *(const bf16x8*)&PsR[(rt * 16 + c) * 72 + g * 8];
                    #pragma unroll
                    for (int ct = 0; ct < 4; ct++)
                        o[rt * 4 + ct] = __builtin_amdgcn_mfma_f32_16x16x32_bf16(
                            pa, bva[ct], o[rt * 4 + ct], 0, 0, 0);
                }
                #pragma unroll
                for (int ct = 0; ct < 4; ct++)   // prefetch V(t, h0) for next tile
                    bva[ct] = *(const bf16x8*)(Vp + (size_t)(ct * 16) * 2048 + t * 64);
                #pragma unroll
                for (int rt = 0; rt < 4; rt++) {
                    bf16x8 pa = *(const bf16x8*)&PsR[(rt * 16 + c) * 72 + 32 + g * 8];
                    #pragma unroll
                    for (int ct = 0; ct < 4; ct++)
                        o[rt * 4 + ct] = __builtin_amdgcn_mfma_f32_16x16x32_bf16(
                            pa, bvb[ct], o[rt * 4 + ct], 0, 0, 0);
                }
            }
        }
        __syncthreads();             // C: Ps(31) + psum_s visible
        {
            const unsigned short* PsR = &Ps[31 & 1][0][0];
            bf16x8 bvb[4];
            #pragma unroll
            for (int ct = 0; ct < 4; ct++)
                bvb[ct] = *(const bf16x8*)(Vp + (size_t)(ct * 16) * 2048 + 31 * 64 + 32);
            #pragma unroll
            for (int rt = 0; rt < 4; rt++) {
                bf16x8 pa = *(const bf16x8*)&PsR[(rt * 16 + c) * 72 + g * 8];
                #pragma unroll
                for (int ct = 0; ct < 4; ct++)
                    o[rt * 4 + ct] = __builtin_amdgcn_mfma_f32_16x16x32_bf16(
                        pa, bva[ct], o[rt * 4 + ct], 0, 0, 0);
            }
            #pragma unroll
            for (int rt = 0; rt < 4; rt++) {
                bf16x8 pa = *(const bf16x8*)&PsR[(rt * 16 + c) * 72 + 32 + g * 8];
                #pragma unroll
                for (int ct = 0; ct < 4; ct++)
                    o[rt * 4 + ct] = __builtin_amdgcn_mfma_f32_16x16x32_bf16(
                        pa, bvb[ct], o[rt * 4 + ct], 0, 0, 0);
            }
        }

        float* ob = out + ((size_t)(b * 2048 + qt * 64)) * 512;
        #pragma unroll
        for (int rt = 0; rt < 4; rt++)
            #pragma unroll
            for (int r = 0; r < 4; r++) {
                int lrow = rt * 16 + g * 4 + r;
                float l = psum_s[lrow][0] + psum_s[lrow][1];
                float inv = 1.0f / l;
                #pragma unroll
                for (int ct = 0; ct < 4; ct++)
                    ob[(size_t)lrow * 512 + pcol + ct * 16 + c] = o[rt * 4 + ct][r] * inv;
            }
    }
}

// ---------------------------------------------------------------------------
extern "C" void kernel_launch(void* const* d_in, const int* in_sizes, int n_in,
                              void* d_out, int out_size, void* d_ws, size_t ws_size,
                              hipStream_t stream) {
    const float* x = (const float*)d_in[0];   // [8][2048][512] fp32
    const float* W = (const float*)d_in[1];   // [3][512][512] fp32
    float* out = (float*)d_out;               // [8][2048][512] fp32
    char* ws = (char*)d_ws;
    unsigned short* WT = (unsigned short*)(ws);
    unsigned short* Q  = (unsigned short*)(ws + (size_t)2  * 1024 * 1024);
    unsigned short* K  = (unsigned short*)(ws + (size_t)18 * 1024 * 1024);
    unsigned short* VT = (unsigned short*)(ws + (size_t)34 * 1024 * 1024);

    wt_kernel<<<192, 256, 0, stream>>>(W, WT);
    proj_kernel<<<1536, 256, 0, stream>>>(x, WT, Q, K, VT);
    attn_kernel<<<256, 1024, 0, stream>>>(Q, K, VT, out);
}

// Round 16
// 140.893 us; speedup vs baseline: 1.0570x; 1.0455x over previous
//
#include <hip/hip_runtime.h>
#include <hip/hip_bf16.h>

typedef __attribute__((ext_vector_type(8))) short bf16x8;
typedef __attribute__((ext_vector_type(4))) float f32x4;

#define DEV static __device__ __forceinline__

DEV unsigned short f2bf(float f) {
    union { __hip_bfloat16 h; unsigned short u; } cv;
    cv.h = __float2bfloat16(f);
    return cv.u;
}

DEV bf16x8 cvt8(f32x4 lo, f32x4 hi) {
    bf16x8 u;
    u[0] = (short)f2bf(lo[0]); u[1] = (short)f2bf(lo[1]);
    u[2] = (short)f2bf(lo[2]); u[3] = (short)f2bf(lo[3]);
    u[4] = (short)f2bf(hi[0]); u[5] = (short)f2bf(hi[1]);
    u[6] = (short)f2bf(hi[2]); u[7] = (short)f2bf(hi[3]);
    return u;
}

typedef __attribute__((address_space(1))) const void gas_t;
typedef __attribute__((address_space(3))) void las_t;

DEV void gl_lds16(const void* g, void* l) {
    __builtin_amdgcn_global_load_lds((gas_t*)g, (las_t*)l, 16, 0, 0);
}

// ---------------------------------------------------------------------------
// Kernel 1 (unchanged): W [3][512][512] fp32 -> WT bf16 transposed.
// W0 pre-scaled by 1/sqrt(512).
// ---------------------------------------------------------------------------
__global__ __launch_bounds__(256, 2) void wt_kernel(const float* __restrict__ W,
                                                    unsigned short* __restrict__ WT) {
    __shared__ __align__(16) unsigned short T[64][72];
    int bid = blockIdx.x;
    int w = bid >> 6;
    int rem = bid & 63;
    int kt = rem >> 3, nt = rem & 7;
    int t = threadIdx.x;
    int r = t >> 2, cq = t & 3;
    const float* src = W + ((size_t)(w * 512 + kt * 64 + r)) * 512 + nt * 64 + cq * 16;
    float sc = (w == 0) ? 0.04419417382415922f : 1.0f;  // 1/sqrt(512)
    #pragma unroll
    for (int i = 0; i < 4; i++) {
        float4 f = *(const float4*)(src + 4 * i);
        T[r][cq * 16 + 4 * i + 0] = f2bf(f.x * sc);
        T[r][cq * 16 + 4 * i + 1] = f2bf(f.y * sc);
        T[r][cq * 16 + 4 * i + 2] = f2bf(f.z * sc);
        T[r][cq * 16 + 4 * i + 3] = f2bf(f.w * sc);
    }
    __syncthreads();
    int n = t >> 2, kq = t & 3;
    bf16x8 v0, v1;
    #pragma unroll
    for (int e = 0; e < 8; e++) v0[e] = (short)T[kq * 16 + e][n];
    #pragma unroll
    for (int e = 0; e < 8; e++) v1[e] = (short)T[kq * 16 + 8 + e][n];
    unsigned short* dst = WT + ((size_t)(w * 512 + nt * 64 + n)) * 512 + kt * 64 + kq * 16;
    *(bf16x8*)dst = v0;
    *(bf16x8*)(dst + 8) = v1;
}

// ---------------------------------------------------------------------------
// Kernel 2 (v18): W-FUSED proj. One block computes Q, K, AND V for its
// (mt, nt) 128x128 tile -> x slab staged ONCE (A-traffic 384->128 MB; total
// L2 reads 576->320 MB) and 48 MFMAs per barrier phase (was 16).
// acc[3][4][4] = 192 VGPR; LDS = As 32KB + Bs 48KB = 80KB -> exactly
// 2 blocks/CU -> 2 waves/SIMD -> 256-VGPR budget under (256,2). Grid 512.
// Schedule/fragment layout/swizzles identical to v11; epilogue = v15's,
// run 3x from the shared Cs overlay.
// ---------------------------------------------------------------------------
#define STAGE_PW(kk) do {                                                         \
    _Pragma("unroll")                                                             \
    for (int i_ = 0; i_ < 4; i_++) {   /* A: fp32, 8 rows/wave/iter */            \
        int r_ = wid * 32 + i_ * 8 + (lane >> 3);                                 \
        int ch_ = (lane & 7) ^ (r_ & 7);                                          \
        gl_lds16(xp + (size_t)r_ * 512 + (kk) * 32 + ch_ * 4,                     \
                 &As[((kk) & 1) * 4096 + (wid * 32 + i_ * 8) * 32]);              \
    }                                                                             \
    _Pragma("unroll")                                                             \
    for (int w_ = 0; w_ < 3; w_++)                                                \
        _Pragma("unroll")                                                         \
        for (int j_ = 0; j_ < 2; j_++) {  /* B: bf16, 16 rows/wave/iter */        \
            int r_ = wid * 32 + j_ * 16 + (lane >> 2);                            \
            int ch_ = (lane & 3) ^ (r_ & 3);                                      \
            gl_lds16(wp + (size_t)(w_ * 512 + r_) * 512 + (kk) * 32 + ch_ * 8,    \
                     &Bs[((kk) & 1) * 12288 + w_ * 4096 + (wid * 32 + j_ * 16) * 32]); \
        }                                                                         \
} while (0)

__global__ __launch_bounds__(256, 2) void proj_kernel(const float* __restrict__ x,
        const unsigned short* __restrict__ WT,
        unsigned short* __restrict__ Qo, unsigned short* __restrict__ Ko,
        unsigned short* __restrict__ VTo) {
    __shared__ __align__(16) char smem[81920];             // 80 KB
    float* As = (float*)smem;                              // [2][128*32] fp32 32KB
    unsigned short* Bs = (unsigned short*)(smem + 32768);  // [2][3][128*32] bf16 48KB
    unsigned short* Cs = (unsigned short*)smem;            // [128][136] (post-loop)

    int bid = blockIdx.x;
    int swz = (bid & 7) * 64 + (bid >> 3);    // XCD-contiguous, 512 blocks
    int mt = swz >> 2, nt = swz & 3;          // 128-row slab x 128-col group
    int tid = threadIdx.x;
    int lane = tid & 63, wid = tid >> 6;
    int wm = wid >> 1, wn = wid & 1;
    int c = lane & 15, g = lane >> 4;

    const float* xp = x + (size_t)(mt * 128) * 512;
    const unsigned short* wp = WT + (size_t)(nt * 128) * 512;

    const f32x4 fz = {0.f, 0.f, 0.f, 0.f};
    f32x4 acc[3][4][4];
    #pragma unroll
    for (int w_ = 0; w_ < 3; w_++)
        #pragma unroll
        for (int i = 0; i < 4; i++)
            #pragma unroll
            for (int j = 0; j < 4; j++) acc[w_][i][j] = fz;

    STAGE_PW(0);
    for (int kk = 0; kk < 16; kk++) {
        __syncthreads();                 // buf[kk&1] DMA drained (vmcnt0)
        if (kk + 1 < 16) STAGE_PW(kk + 1);
        const float* Ac = &As[(kk & 1) * 4096];
        bf16x8 a[4];
        #pragma unroll
        for (int rt = 0; rt < 4; rt++) {
            int row = wm * 64 + rt * 16 + c;
            f32x4 lo = *(const f32x4*)&Ac[row * 32 + (((2 * g) ^ (row & 7)) * 4)];
            f32x4 hi = *(const f32x4*)&Ac[row * 32 + (((2 * g + 1) ^ (row & 7)) * 4)];
            a[rt] = cvt8(lo, hi);
        }
        #pragma unroll
        for (int w_ = 0; w_ < 3; w_++) {
            const unsigned short* Bc = &Bs[(kk & 1) * 12288 + w_ * 4096];
            bf16x8 bb[4];
            #pragma unroll
            for (int ct = 0; ct < 4; ct++) {
                int row = wn * 64 + ct * 16 + c;
                bb[ct] = *(const bf16x8*)&Bc[row * 32 + ((g ^ (row & 3)) * 8)];
            }
            __builtin_amdgcn_s_setprio(1);
            #pragma unroll
            for (int rt = 0; rt < 4; rt++)
                #pragma unroll
                for (int ct = 0; ct < 4; ct++)
                    acc[w_][rt][ct] = __builtin_amdgcn_mfma_f32_16x16x32_bf16(
                        a[rt], bb[ct], acc[w_][rt][ct], 0, 0, 0);
            __builtin_amdgcn_s_setprio(0);
        }
    }

    // ---- epilogue: per w, stage 128x128 bf16 tile into Cs then stream out
    #pragma unroll
    for (int w_ = 0; w_ < 3; w_++) {
        __syncthreads();                 // previous Cs consumers / staging done
        #pragma unroll
        for (int rt = 0; rt < 4; rt++)
            #pragma unroll
            for (int ct = 0; ct < 4; ct++)
                #pragma unroll
                for (int r = 0; r < 4; r++)
                    Cs[(wm * 64 + rt * 16 + g * 4 + r) * 136 + (wn * 64 + ct * 16 + c)] =
                        f2bf(acc[w_][rt][ct][r]);
        __syncthreads();

        if (w_ < 2) {
            // Q/K: row-major, coalesced — 16 lanes cover one 256B row segment
            unsigned short* dst = (w_ == 0) ? Qo : Ko;
            int rr = tid >> 4;           // 0..15
            int cc8 = (tid & 15) * 8;    // 0..120
            #pragma unroll
            for (int jj = 0; jj < 8; jj++) {
                int row = jj * 16 + rr;
                bf16x8 v = *(const bf16x8*)&Cs[row * 136 + cc8];
                *(bf16x8*)(dst + (size_t)(mt * 128 + row) * 512 + nt * 128 + cc8) = v;
            }
        } else {
            // V: transposed out of Cs -> VT [8][512][2048]
            int dcol = tid >> 1, sh = tid & 1;
            int bb2 = mt >> 4;
            int s0r = (mt & 15) * 128;
            #pragma unroll
            for (int jj = 0; jj < 8; jj++) {
                bf16x8 v;
                #pragma unroll
                for (int e = 0; e < 8; e++) v[e] = (short)Cs[(sh * 64 + jj * 8 + e) * 136 + dcol];
                *(bf16x8*)(VTo + ((size_t)(bb2 * 512 + nt * 128 + dcol)) * 2048 + s0r + sh * 64 + jj * 8) = v;
            }
        }
    }
}

// ---------------------------------------------------------------------------
// Kernel 3 (v10/v8 verbatim, FROZEN): wave-specialized flash attention
// + PV V-tile prefetch. 113.4 us. Six scheduling/bank experiments were all
// null/negative; residual conflicts are the K-read structural minimum.
// ---------------------------------------------------------------------------
#define STAGE_K(tt) do {                                                        \
    _Pragma("unroll")                                                           \
    for (int i_ = 0; i_ < 4; i_++) {                                            \
        int r_ = wid * 4 + i_;                                                  \
        gl_lds16(Kb + (size_t)((tt) * 64 + r_) * 512 + ((lane ^ (r_ & 7)) * 8), \
                 &Ks[(tt) & 1][r_ * 512]);                                      \
    }                                                                           \
} while (0)

__global__ __launch_bounds__(1024, 4) void attn_kernel(const unsigned short* __restrict__ Qg,
        const unsigned short* __restrict__ Kg, const unsigned short* __restrict__ VTg,
        float* __restrict__ out) {
    __shared__ __align__(16) unsigned short Ks[2][64 * 512];  // 128 KB, swizzled
    __shared__ __align__(16) unsigned short Ps[2][64][72];    // 18.4 KB, dbuf
    __shared__ float psum_s[64][2];

    int bid = blockIdx.x;
    int swz = (bid & 7) * 32 + (bid >> 3);  // XCD x owns batch x
    int b = swz >> 5, qt = swz & 31;
    int tid = threadIdx.x;
    int lane = tid & 63, wid = tid >> 6;    // wid 0..15
    int c = lane & 15, g = lane >> 4;

    const unsigned short* Qb = Qg + ((size_t)(b * 2048 + qt * 64)) * 512;
    const unsigned short* Kb = Kg + ((size_t)b * 2048) * 512;
    const unsigned short* Vb = VTg + ((size_t)b * 512) * 2048;

    // ---- stage Q (swizzled source) into Ks[0] — all waves
    #pragma unroll
    for (int i = 0; i < 4; i++) {
        int r = wid * 4 + i;
        gl_lds16(Qb + (size_t)r * 512 + ((lane ^ (r & 7)) * 8), &Ks[0][r * 512]);
    }

    if (wid < 8) {
        // ================= score waves =================
        int sqg = wid >> 1;          // q-row group (0..3), two waves each
        int skg = (wid & 1) * 2;     // first of two 16-col kv groups (0 or 2)
        __syncthreads();             // A: Q DMA done (vmcnt0)
        bf16x8 qf[16];
        {
            int row = sqg * 16 + c;
            #pragma unroll
            for (int ks = 0; ks < 16; ks++)
                qf[ks] = *(const bf16x8*)&Ks[0][row * 512 + (((ks * 4 + g) ^ (row & 7)) * 8)];
        }
        __syncthreads();             // B: Q reads done before K(0) overwrite
        STAGE_K(0);

        float accs[8];
        #pragma unroll
        for (int j = 0; j < 8; j++) accs[j] = 0.0f;

        for (int t = 0; t < 32; t++) {
            __syncthreads();         // K(t) staged; Ps(t) buffer free
            if (t + 1 < 32) STAGE_K(t + 1);

            const unsigned short* KsC = &Ks[t & 1][0];
            const f32x4 fz = {0.f, 0.f, 0.f, 0.f};
            f32x4 s0 = fz, s1 = fz;
            int kr0 = skg * 16 + c;
            int kr1 = kr0 + 16;
            #pragma unroll
            for (int ks = 0; ks < 16; ks++) {
                bf16x8 bk0 = *(const bf16x8*)&KsC[kr0 * 512 + (((ks * 4 + g) ^ (kr0 & 7)) * 8)];
                bf16x8 bk1 = *(const bf16x8*)&KsC[kr1 * 512 + (((ks * 4 + g) ^ (kr1 & 7)) * 8)];
                s0 = __builtin_amdgcn_mfma_f32_16x16x32_bf16(qf[ks], bk0, s0, 0, 0, 0);
                s1 = __builtin_amdgcn_mfma_f32_16x16x32_bf16(qf[ks], bk1, s1, 0, 0, 0);
            }
            unsigned short* PsW = &Ps[t & 1][0][0];
            #pragma unroll
            for (int r = 0; r < 4; r++) {
                int row = sqg * 16 + g * 4 + r;
                float p0 = __expf(s0[r]);
                float p1 = __expf(s1[r]);
                accs[r] += p0;
                accs[4 + r] += p1;
                PsW[row * 72 + skg * 16 + c] = f2bf(p0);
                PsW[row * 72 + (skg + 1) * 16 + c] = f2bf(p1);
            }
        }

        // final row-sum reduction into psum_s
        #pragma unroll
        for (int r = 0; r < 4; r++) {
            float v = accs[r] + accs[4 + r];
            v += __shfl_xor(v, 1);
            v += __shfl_xor(v, 2);
            v += __shfl_xor(v, 4);
            v += __shfl_xor(v, 8);
            if (c == 0) psum_s[sqg * 16 + g * 4 + r][wid & 1] = v;
        }
        __syncthreads();             // C: Ps(31) + psum_s published
    } else {
        // ================= PV waves =================
        int pcol = (wid - 8) * 64;   // d-column base (0..448)
        const unsigned short* Vp = Vb + (size_t)(pcol + c) * 2048 + g * 8;
        __syncthreads();             // A
        __syncthreads();             // B
        STAGE_K(0);

        f32x4 o[16];
        {
            const f32x4 fz = {0.f, 0.f, 0.f, 0.f};
            #pragma unroll
            for (int i = 0; i < 16; i++) o[i] = fz;
        }
        bf16x8 bva[4];               // V(t, h0) prefetched one tile ahead
        #pragma unroll
        for (int ct = 0; ct < 4; ct++)
            bva[ct] = *(const bf16x8*)(Vp + (size_t)(ct * 16) * 2048);

        for (int t = 0; t < 32; t++) {
            __syncthreads();         // K(t) staged; Ps(t-1) visible
            if (t + 1 < 32) STAGE_K(t + 1);
            if (t > 0) {
                int tp = t - 1;
                const unsigned short* PsR = &Ps[tp & 1][0][0];
                bf16x8 bvb[4];       // V(tp, h1): issue now, use after h0 MFMAs
                #pragma unroll
                for (int ct = 0; ct < 4; ct++)
                    bvb[ct] = *(const bf16x8*)(Vp + (size_t)(ct * 16) * 2048 + tp * 64 + 32);
                #pragma unroll
                for (int rt = 0; rt < 4; rt++) {
                    bf16x8 pa = *(const bf16x8*)&PsR[(rt * 16 + c) * 72 + g * 8];
                    #pragma unroll
                    for (int ct = 0; ct < 4; ct++)
                        o[rt * 4 + ct] = __builtin_amdgcn_mfma_f32_16x16x32_bf16(
                            pa, bva[ct], o[rt * 4 + ct], 0, 0, 0);
                }
                #pragma unroll
                for (int ct = 0; ct < 4; ct++)   // prefetch V(t, h0) for next tile
                    bva[ct] = *(const bf16x8*)(Vp + (size_t)(ct * 16) * 2048 + t * 64);
                #pragma unroll
                for (int rt = 0; rt < 4; rt++) {
                    bf16x8 pa = *(const bf16x8*)&PsR[(rt * 16 + c) * 72 + 32 + g * 8];
                    #pragma unroll
                    for (int ct = 0; ct < 4; ct++)
                        o[rt * 4 + ct] = __builtin_amdgcn_mfma_f32_16x16x32_bf16(
                            pa, bvb[ct], o[rt * 4 + ct], 0, 0, 0);
                }
            }
        }
        __syncthreads();             // C: Ps(31) + psum_s visible
        {
            const unsigned short* PsR = &Ps[31 & 1][0][0];
            bf16x8 bvb[4];
            #pragma unroll
            for (int ct = 0; ct < 4; ct++)
                bvb[ct] = *(const bf16x8*)(Vp + (size_t)(ct * 16) * 2048 + 31 * 64 + 32);
            #pragma unroll
            for (int rt = 0; rt < 4; rt++) {
                bf16x8 pa = *(const bf16x8*)&PsR[(rt * 16 + c) * 72 + g * 8];
                #pragma unroll
                for (int ct = 0; ct < 4; ct++)
                    o[rt * 4 + ct] = __builtin_amdgcn_mfma_f32_16x16x32_bf16(
                        pa, bva[ct], o[rt * 4 + ct], 0, 0, 0);
            }
            #pragma unroll
            for (int rt = 0; rt < 4; rt++) {
                bf16x8 pa = *(const bf16x8*)&PsR[(rt * 16 + c) * 72 + 32 + g * 8];
                #pragma unroll
                for (int ct = 0; ct < 4; ct++)
                    o[rt * 4 + ct] = __builtin_amdgcn_mfma_f32_16x16x32_bf16(
                        pa, bvb[ct], o[rt * 4 + ct], 0, 0, 0);
            }
        }

        float* ob = out + ((size_t)(b * 2048 + qt * 64)) * 512;
        #pragma unroll
        for (int rt = 0; rt < 4; rt++)
            #pragma unroll
            for (int r = 0; r < 4; r++) {
                int lrow = rt * 16 + g * 4 + r;
                float l = psum_s[lrow][0] + psum_s[lrow][1];
                float inv = 1.0f / l;
                #pragma unroll
                for (int ct = 0; ct < 4; ct++)
                    ob[(size_t)lrow * 512 + pcol + ct * 16 + c] = o[rt * 4 + ct][r] * inv;
            }
    }
}

// ---------------------------------------------------------------------------
extern "C" void kernel_launch(void* const* d_in, const int* in_sizes, int n_in,
                              void* d_out, int out_size, void* d_ws, size_t ws_size,
                              hipStream_t stream) {
    const float* x = (const float*)d_in[0];   // [8][2048][512] fp32
    const float* W = (const float*)d_in[1];   // [3][512][512] fp32
    float* out = (float*)d_out;               // [8][2048][512] fp32
    char* ws = (char*)d_ws;
    unsigned short* WT = (unsigned short*)(ws);
    unsigned short* Q  = (unsigned short*)(ws + (size_t)2  * 1024 * 1024);
    unsigned short* K  = (unsigned short*)(ws + (size_t)18 * 1024 * 1024);
    unsigned short* VT = (unsigned short*)(ws + (size_t)34 * 1024 * 1024);

    wt_kernel<<<192, 256, 0, stream>>>(W, WT);
    proj_kernel<<<512, 256, 0, stream>>>(x, WT, Q, K, VT);
    attn_kernel<<<256, 1024, 0, stream>>>(Q, K, VT, out);
}